// Round 19
// baseline (190.703 us; speedup 1.0000x reference)
//
#include <hip/hip_runtime.h>

// PolyRPE attention, MI355X gfx950.
// prep (cvt + LDS-tiled transposes) -> QKV GEMM (256x256, BK=64 as 24 k32
// halves, 8 waves, 2-phase-per-half interleave, counted vmcnt(8), 128 KB
// 4-slot LDS, T2 swizzle, T1 XCD grid; m201-style schedule) -> fused flash
// attention v5 (KVBLK=128, MFMA L-sums, trunc P-pack) -> proj GEMM (same).
//
// Dims: B=16, N=577 (pad 640), C=768, h=12, d=64, K=768, 3C=2304.

using u16 = unsigned short;
using u32 = unsigned int;

typedef __bf16 bf16x8 __attribute__((ext_vector_type(8)));
typedef float f32x4 __attribute__((ext_vector_type(4)));

__device__ inline u16 f2bf(float f) {
    u32 u = __builtin_bit_cast(u32, f);
    u32 r = u + 0x7fffu + ((u >> 16) & 1u);   // RNE
    return (u16)(r >> 16);
}
__device__ inline float bf2f(u16 x) {
    return __builtin_bit_cast(float, (u32)x << 16);
}

__device__ inline f32x4 mfma16(bf16x8 a, bf16x8 b, f32x4 c) {
    return __builtin_amdgcn_mfma_f32_16x16x32_bf16(a, b, c, 0, 0, 0);
}

__device__ inline float fexp2(float x) { return __builtin_amdgcn_exp2f(x); }

// bijective XCD chunk remap (m204)
__device__ inline int xcd_remap(int bid, int nwg) {
    const int q = nwg >> 3, r = nwg & 7;
    const int xcd = bid & 7, idx = bid >> 3;
    return (xcd < r ? xcd * (q + 1) : r * (q + 1) + (xcd - r) * q) + idx;
}

// 16-lane (DPP-row) max reduction.
__device__ inline float dpp_max16(float v) {
    int x;
    x = __builtin_amdgcn_update_dpp(0, __builtin_bit_cast(int, v), 0xB1, 0xF, 0xF, true);
    v = fmaxf(v, __builtin_bit_cast(float, x));
    x = __builtin_amdgcn_update_dpp(0, __builtin_bit_cast(int, v), 0x4E, 0xF, 0xF, true);
    v = fmaxf(v, __builtin_bit_cast(float, x));
    x = __builtin_amdgcn_update_dpp(0, __builtin_bit_cast(int, v), 0x124, 0xF, 0xF, true);
    v = fmaxf(v, __builtin_bit_cast(float, x));
    x = __builtin_amdgcn_update_dpp(0, __builtin_bit_cast(int, v), 0x128, 0xF, 0xF, true);
    v = fmaxf(v, __builtin_bit_cast(float, x));
    return v;
}

#define GLOAD_LDS16(g, l)                                                          \
    __builtin_amdgcn_global_load_lds((const __attribute__((address_space(1))) u32*)(g), \
                                     (__attribute__((address_space(3))) u32*)(l), 16, 0, 0)

#define BAR()    asm volatile("s_barrier" ::: "memory")
#define WAITV8() asm volatile("s_waitcnt vmcnt(8)" ::: "memory")
#define WAITV4() asm volatile("s_waitcnt vmcnt(4)" ::: "memory")
#define WAITV0() asm volatile("s_waitcnt vmcnt(0)" ::: "memory")

// ---------------- prep ----------------
__global__ void k_prep(const float* __restrict__ x, const float* __restrict__ Wq,
                       const float* __restrict__ Wp, u16* __restrict__ xb,
                       u16* __restrict__ wqkv, u16* __restrict__ wprj) {
    const int bid = blockIdx.x;
    const int t = threadIdx.x;
    if (bid < 576) {
        __shared__ float tile[64][65];
        const float* src;
        u16* dst;
        int C, rt, ct;
        if (bid < 432) { src = Wq; dst = wqkv; C = 2304; rt = bid / 36; ct = bid % 36; }
        else { const int b2 = bid - 432; src = Wp; dst = wprj; C = 768; rt = b2 / 12; ct = b2 % 12; }
        const int row0 = rt * 64, col0 = ct * 64;
#pragma unroll
        for (int it = 0; it < 4; ++it) {
            const int row = it * 16 + (t >> 4);
            const float4 v = *(const float4*)&src[(size_t)(row0 + row) * C + col0 + (t & 15) * 4];
            tile[row][(t & 15) * 4 + 0] = v.x;
            tile[row][(t & 15) * 4 + 1] = v.y;
            tile[row][(t & 15) * 4 + 2] = v.z;
            tile[row][(t & 15) * 4 + 3] = v.w;
        }
        __syncthreads();
#pragma unroll
        for (int it = 0; it < 4; ++it) {
            const int oc = it * 16 + (t >> 4);
            const int orr = (t & 15) * 4;
            ushort4 o;
            o.x = f2bf(tile[orr + 0][oc]);
            o.y = f2bf(tile[orr + 1][oc]);
            o.z = f2bf(tile[orr + 2][oc]);
            o.w = f2bf(tile[orr + 3][oc]);
            *(ushort4*)&dst[(size_t)(col0 + oc) * 768 + row0 + orr] = o;
        }
    } else {
        const int n4 = 9232 * 768 / 4;
        const int stride = (2048 - 576) * 256;
        for (int i = (bid - 576) * 256 + t; i < n4; i += stride) {
            float4 v = ((const float4*)x)[i];
            ushort4 o;
            o.x = f2bf(v.x); o.y = f2bf(v.y); o.z = f2bf(v.z); o.w = f2bf(v.w);
            ((ushort4*)xb)[i] = o;
        }
    }
}

// ---------------- GEMM v2: 256x256, 8 waves, 2-phase halves ------------------
// C[M x N] = A[M x 768] * Bw^T, Bw [N][768] bf16. 24 k32-halves; LDS 4 slots
// x (A[256][32] + B[256][32]); swizzle chunk^((row>>1)&3) (r8-proven, 0-conf).
// Per half: 2 phases {ds_read frags | 2 gl_lds of half H+3 | BAR | 16 MFMA |
// BAR}; counted vmcnt(8) once/half (tail 4->0). Prefetch depth 3 halves.
// MODE 0: QKV scatter -> Q/K [bh][640][64], Vt [bh][64][640]; MODE 1: fp32+bias.
template <int MODE, int NB>
__launch_bounds__(512, 2)
__global__ void k_gemm2(const u16* __restrict__ A, const u16* __restrict__ Bw,
                        u16* __restrict__ q_out, u16* __restrict__ k_out,
                        u16* __restrict__ v_out,
                        float* __restrict__ f_out, const float* __restrict__ bias) {
    constexpr int M = 9232;
    extern __shared__ u16 lds[];              // 65536 u16 = 128 KB
    const int wgid = xcd_remap(blockIdx.x, gridDim.x);
    const int mbase = (wgid / NB) * 256;
    const int nbase = (wgid - (wgid / NB) * NB) * 256;
    const int tid = threadIdx.x;
    const int lane = tid & 63, w = tid >> 6;
    const int lr = lane & 15, lg = lane >> 4;
    const int wm = w >> 2, wn = w & 3;        // 2 x 4 waves, wave tile 128x64
    const u16* Ag = A + (size_t)mbase * 768;
    const u16* Bg = Bw + (size_t)nbase * 768;
    f32x4 acc[8][4] = {};

    // stage 2 chunks of half H: part 0 = A[256][32], part 1 = B[256][32]
    auto stage2 = [&](int H, int part) {
        const int koff = (H >> 1) * 64 + (H & 1) * 32;
        const u16* G = part ? Bg : Ag;
        u16* D = lds + (part ? 32768 : 0) + (H & 3) * 8192;
#pragma unroll
        for (int l = 0; l < 2; ++l) {
            const int p = l * 512 + tid;
            const int row = p >> 2, chp = p & 3;
            GLOAD_LDS16(G + (size_t)row * 768 + koff + ((chp ^ ((row >> 1) & 3)) * 8),
                        D + p * 8);
        }
    };
    auto ldfrag = [&](const u16* base, int row) {
        return *(const bf16x8*)(base + row * 32 + ((lg ^ ((row >> 1) & 3)) * 8));
    };

    // prologue: halves 0,1,2 (12 loads/thread)
    stage2(0, 0); stage2(0, 1);
    stage2(1, 0); stage2(1, 1);
    stage2(2, 0); stage2(2, 1);
    WAITV8();          // half 0 resident; halves 1,2 in flight
    BAR();

    for (int H = 0; H < 24; ++H) {
        const u16* Ah = lds + (H & 3) * 8192;
        const u16* Bh = lds + 32768 + (H & 3) * 8192;
        const bool pre = (H + 3) < 24;
        bf16x8 bv[4], af[4];
        // ---- phase 0: B frags + A frags m0..3; stage A-part of H+3
#pragma unroll
        for (int n = 0; n < 4; ++n) bv[n] = ldfrag(Bh, wn * 64 + n * 16 + lr);
#pragma unroll
        for (int m = 0; m < 4; ++m) af[m] = ldfrag(Ah, wm * 128 + m * 16 + lr);
        if (pre) stage2(H + 3, 0);
        BAR();
        __builtin_amdgcn_s_setprio(1);
#pragma unroll
        for (int m = 0; m < 4; ++m)
#pragma unroll
            for (int n = 0; n < 4; ++n)
                acc[m][n] = mfma16(af[m], bv[n], acc[m][n]);
        __builtin_amdgcn_s_setprio(0);
        BAR();
        // ---- phase 1: A frags m4..7 (B regs reused); stage B-part of H+3
#pragma unroll
        for (int m = 0; m < 4; ++m) af[m] = ldfrag(Ah, wm * 128 + (m + 4) * 16 + lr);
        if (pre) stage2(H + 3, 1);
        BAR();
        __builtin_amdgcn_s_setprio(1);
#pragma unroll
        for (int m = 0; m < 4; ++m)
#pragma unroll
            for (int n = 0; n < 4; ++n)
                acc[m + 4][n] = mfma16(af[m], bv[n], acc[m + 4][n]);
        __builtin_amdgcn_s_setprio(0);
        // counted drain: half H+1 must be resident before next phase-0 reads
        if (H < 23) {
            if (H <= 20)      { WAITV8(); }   // H+2,H+3 stay in flight
            else if (H == 21) { WAITV4(); }   // only H+2=23 in flight
            else              { WAITV0(); }
        }
        BAR();
    }

    // ---- epilogue
#pragma unroll
    for (int m = 0; m < 8; ++m) {
#pragma unroll
        for (int n = 0; n < 4; ++n) {
            const int col = nbase + wn * 64 + n * 16 + lr;
#pragma unroll
            for (int r = 0; r < 4; ++r) {
                const int row = mbase + wm * 128 + m * 16 + 4 * lg + r;
                if (row < M) {
                    if (MODE == 0) {
                        const int bb = row / 577;
                        const int nn = row - bb * 577;
                        const int tt = col / 768;
                        const int rem = col - tt * 768;
                        const int hh = rem >> 6, dd = rem & 63;
                        const size_t bh = (size_t)bb * 12 + hh;
                        const u16 val = f2bf(acc[m][n][r]);
                        if (tt == 0)      q_out[(bh * 640 + nn) * 64 + dd] = val;
                        else if (tt == 1) k_out[(bh * 640 + nn) * 64 + dd] = val;
                        else              v_out[(bh * 64 + dd) * 640 + nn] = val;
                    } else {
                        f_out[(size_t)row * 768 + col] = acc[m][n][r] + bias[col];
                    }
                }
            }
        }
    }
}

// ---------------- fused attention v5 (KVBLK=128, all 577 q rows) ------------
__launch_bounds__(256, 2)
__global__ void k_attn(const u16* __restrict__ Qg, const u16* __restrict__ Kg,
                       const u16* __restrict__ Vtg, const float* __restrict__ coef,
                       u16* __restrict__ Og) {
    const int wgid = xcd_remap(blockIdx.x, gridDim.x);   // 960 = 8*120 exact
    const int bh = wgid / 5;
    const int qt = wgid - bh * 5;       // 0..4
    const int b = bh / 12, h = bh - b * 12;
    const int t = threadIdx.x;
    const int lane = t & 63, w = t >> 6;
    const int lr = lane & 15, lg = lane >> 4;
    __shared__ alignas(16) u16 Kl[2][8192];   // [128 keys][64 d]
    __shared__ alignas(16) u16 Vl[2][8192];   // [64 d][128 keys]

    const float l2e = 1.4426950408889634f;
    const float hc0 = coef[h * 4 + 0] * l2e, hc1 = coef[h * 4 + 1] * l2e,
                hc2 = coef[h * 4 + 2] * l2e, hc3 = coef[h * 4 + 3] * l2e;

    bf16x8 onesv;
#pragma unroll
    for (int j = 0; j < 8; ++j) onesv[j] = (__bf16)1.0f;

    const int qrow0 = qt * 128 + w * 32;
    bf16x8 qa[2][2];
#pragma unroll
    for (int i = 0; i < 2; ++i) {
        const u16* qp = Qg + ((size_t)bh * 640 + qrow0 + i * 16 + lr) * 64;
        qa[i][0] = *(const bf16x8*)(qp + lg * 8);
        qa[i][1] = *(const bf16x8*)(qp + 32 + lg * 8);
    }

    float gi[2][4], gj[2][4], nvf[2][4];
#pragma unroll
    for (int i = 0; i < 2; ++i)
#pragma unroll
        for (int r = 0; r < 4; ++r) {
            const int n = qrow0 + i * 16 + 4 * lg + r;
            nvf[i][r] = (n == 0) ? 0.f : 1.f;
            const int nm1 = (n > 0) ? n - 1 : 0;
            const int qi = nm1 / 24;
            gi[i][r] = (float)qi;
            gj[i][r] = (float)(nm1 - qi * 24);
        }

    float M[2][4];
    f32x4 Lac[2] = {};
#pragma unroll
    for (int i = 0; i < 2; ++i)
#pragma unroll
        for (int r = 0; r < 4; ++r) M[i][r] = -3e38f;
    f32x4 acco[2][4] = {};
    const float scale2 = 0.125f * 1.4426950408889634f;
    const int ch0 = ((lg ^ (lr & 7))) * 8;    // K read chunk (d-dim)

    const u16* Ksb = Kg + (size_t)bh * 640 * 64;
    const u16* Vsb = Vtg + (size_t)bh * 64 * 640;
    const int krow = 32 * w + (lane >> 1), kch0 = (lane & 1) * 4;
    const int vrow = 16 * w + (lane >> 2), vch0 = (lane & 3) * 4;

    {   // prologue: tile 0 -> regs -> LDS buf 0
#pragma unroll
        for (int q = 0; q < 4; ++q) {
            uint4 kv = *(const uint4*)(Ksb + (size_t)krow * 64 + (kch0 + q) * 8);
            *(uint4*)(&Kl[0][krow * 64 + (((kch0 + q) ^ (krow & 7)) * 8)]) = kv;
            uint4 vv = *(const uint4*)(Vsb + (size_t)vrow * 640 + (vch0 + q) * 8);
            *(uint4*)(&Vl[0][vrow * 128 + (((vch0 + q) ^ (vrow & 15)) * 8)]) = vv;
        }
    }
    __syncthreads();
    int cur = 0;

    for (int kt = 0; kt < 4; ++kt) {
        const u16* Kc = &Kl[cur][0];
        const u16* Vc = &Vl[cur][0];
        u16* pb0 = &Kl[cur ^ 1][32 * w * 64];
        u16* pb1 = &Vl[cur ^ 1][16 * w * 128];

        f32x4 sac[2][8];
        __builtin_amdgcn_s_setprio(1);
#pragma unroll
        for (int cb = 0; cb < 8; ++cb) {
            const int row = cb * 16 + lr;
            const bf16x8 kb0 = *(const bf16x8*)(Kc + row * 64 + ch0);
            const bf16x8 kb1 = *(const bf16x8*)(Kc + row * 64 + (ch0 ^ 32));
#pragma unroll
            for (int i = 0; i < 2; ++i) {
                f32x4 z = {};
                z = mfma16(qa[i][0], kb0, z);
                sac[i][cb] = mfma16(qa[i][1], kb1, z);
            }
        }
        __builtin_amdgcn_s_setprio(0);

        float tm[2][4];
#pragma unroll
        for (int i = 0; i < 2; ++i)
#pragma unroll
            for (int r = 0; r < 4; ++r) tm[i][r] = -3e38f;
#pragma unroll
        for (int cb = 0; cb < 8; ++cb) {
            const int m = kt * 128 + cb * 16 + lr;
            const float mvf = (m == 0) ? 0.f : 1.f;
            const int mm1 = (m > 0) ? m - 1 : 0;
            const int pi = mm1 / 24;
            const float ci = (float)pi;
            const float cj = (float)(mm1 - pi * 24);
#pragma unroll
            for (int i = 0; i < 2; ++i)
#pragma unroll
                for (int r = 0; r < 4; ++r) {
                    const float d = fabsf(gi[i][r] - ci) + fabsf(gj[i][r] - cj);
                    float rp = fmaf(hc3, d, hc2);
                    rp = fmaf(rp, d, hc1);
                    rp = fmaf(rp, d, hc0);
                    const float v = fmaf(sac[i][cb][r], scale2,
                                         rp * (mvf * nvf[i][r]));
                    sac[i][cb][r] = v;
                    tm[i][r] = fmaxf(tm[i][r], v);
                }
        }
#pragma unroll
        for (int i = 0; i < 2; ++i)
#pragma unroll
            for (int r = 0; r < 4; ++r) tm[i][r] = dpp_max16(tm[i][r]);

        float over = -3e38f;
#pragma unroll
        for (int i = 0; i < 2; ++i)
#pragma unroll
            for (int r = 0; r < 4; ++r) over = fmaxf(over, tm[i][r] - M[i][r]);
        if (__any(over > 11.5f)) {
#pragma unroll
            for (int i = 0; i < 2; ++i)
#pragma unroll
                for (int r = 0; r < 4; ++r) {
                    const float Mn = fmaxf(M[i][r], tm[i][r]);
                    const float a = fexp2(M[i][r] - Mn);
                    Lac[i][r] *= a;
                    acco[i][0][r] *= a; acco[i][1][r] *= a;
                    acco[i][2][r] *= a; acco[i][3][r] *= a;
                    M[i][r] = Mn;
                }
        }

#pragma unroll
        for (int i = 0; i < 2; ++i) {
            u16* pb = i ? pb1 : pb0;
#pragma unroll
            for (int cb = 0; cb < 8; ++cb)
#pragma unroll
                for (int r = 0; r < 4; ++r) {
                    const float p = fexp2(sac[i][cb][r] - M[i][r]);
                    const int rw = 4 * lg + r;
                    pb[rw * 128 + (((2 * cb + (lr >> 3)) ^ (rw & 15)) * 8) + (lr & 7)] =
                        (u16)(__builtin_bit_cast(u32, p) >> 16);
                }
        }

        uint4 nk[4], nv[4];
        {
            const u16* Ks = Ksb + (size_t)(kt + 1) * 128 * 64;
            const u16* Vs = Vsb + (size_t)(kt + 1) * 128;
#pragma unroll
            for (int q = 0; q < 4; ++q) {
                nk[q] = *(const uint4*)(Ks + (size_t)krow * 64 + (kch0 + q) * 8);
                nv[q] = *(const uint4*)(Vs + (size_t)vrow * 640 + (vch0 + q) * 8);
            }
        }

        __builtin_amdgcn_s_setprio(1);
#pragma unroll
        for (int s = 0; s < 4; ++s) {
            const bf16x8 pa0 = *(const bf16x8*)(pb0 + lr * 128 + (((4 * s + lg) ^ (lr & 15)) * 8));
            const bf16x8 pa1 = *(const bf16x8*)(pb1 + lr * 128 + (((4 * s + lg) ^ (lr & 15)) * 8));
            Lac[0] = mfma16(pa0, onesv, Lac[0]);
            Lac[1] = mfma16(pa1, onesv, Lac[1]);
#pragma unroll
            for (int f = 0; f < 4; ++f) {
                const int vr = f * 16 + lr;
                const bf16x8 vb = *(const bf16x8*)(Vc + vr * 128 + (((4 * s + lg) ^ (vr & 15)) * 8));
                acco[0][f] = mfma16(pa0, vb, acco[0][f]);
                acco[1][f] = mfma16(pa1, vb, acco[1][f]);
            }
        }
        __builtin_amdgcn_s_setprio(0);

#pragma unroll
        for (int q = 0; q < 4; ++q) {
            *(uint4*)(&Kl[cur ^ 1][krow * 64 + (((kch0 + q) ^ (krow & 7)) * 8)]) = nk[q];
            *(uint4*)(&Vl[cur ^ 1][vrow * 128 + (((vch0 + q) ^ (vrow & 15)) * 8)]) = nv[q];
        }
        __syncthreads();
        cur ^= 1;
    }

    {   // ---- peeled tail (keys 512..639): cb 0..3 full, cb4 only key 576 ----
        const u16* Kc = &Kl[cur][0];
        const u16* Vc = &Vl[cur][0];
        u16* pb0 = &Kl[cur ^ 1][32 * w * 64];
        u16* pb1 = &Vl[cur ^ 1][16 * w * 128];

        f32x4 sac[2][5];
        __builtin_amdgcn_s_setprio(1);
#pragma unroll
        for (int cb = 0; cb < 5; ++cb) {
            const int row = cb * 16 + lr;
            const bf16x8 kb0 = *(const bf16x8*)(Kc + row * 64 + ch0);
            const bf16x8 kb1 = *(const bf16x8*)(Kc + row * 64 + (ch0 ^ 32));
#pragma unroll
            for (int i = 0; i < 2; ++i) {
                f32x4 z = {};
                z = mfma16(qa[i][0], kb0, z);
                sac[i][cb] = mfma16(qa[i][1], kb1, z);
            }
        }
        __builtin_amdgcn_s_setprio(0);

        float tm[2][4];
#pragma unroll
        for (int i = 0; i < 2; ++i)
#pragma unroll
            for (int r = 0; r < 4; ++r) tm[i][r] = -3e38f;
#pragma unroll
        for (int cb = 0; cb < 5; ++cb) {
            const int m = 512 + cb * 16 + lr;
            const bool valid = (m <= 576);
            const int mm1 = m - 1;
            const int pi = mm1 / 24;
            const float ci = (float)((pi < 24) ? pi : 23);
            const float cj = (float)((pi < 24) ? (mm1 - pi * 24) : 23);
#pragma unroll
            for (int i = 0; i < 2; ++i)
#pragma unroll
                for (int r = 0; r < 4; ++r) {
                    const float d = fabsf(gi[i][r] - ci) + fabsf(gj[i][r] - cj);
                    float rp = fmaf(hc3, d, hc2);
                    rp = fmaf(rp, d, hc1);
                    rp = fmaf(rp, d, hc0);
                    float v = fmaf(sac[i][cb][r], scale2, rp * nvf[i][r]);
                    v = valid ? v : -1e30f;
                    sac[i][cb][r] = v;
                    tm[i][r] = fmaxf(tm[i][r], v);
                }
        }
#pragma unroll
        for (int i = 0; i < 2; ++i)
#pragma unroll
            for (int r = 0; r < 4; ++r) tm[i][r] = dpp_max16(tm[i][r]);

        float over = -3e38f;
#pragma unroll
        for (int i = 0; i < 2; ++i)
#pragma unroll
            for (int r = 0; r < 4; ++r) over = fmaxf(over, tm[i][r] - M[i][r]);
        if (__any(over > 11.5f)) {
#pragma unroll
            for (int i = 0; i < 2; ++i)
#pragma unroll
                for (int r = 0; r < 4; ++r) {
                    const float Mn = fmaxf(M[i][r], tm[i][r]);
                    const float a = fexp2(M[i][r] - Mn);
                    Lac[i][r] *= a;
                    acco[i][0][r] *= a; acco[i][1][r] *= a;
                    acco[i][2][r] *= a; acco[i][3][r] *= a;
                    M[i][r] = Mn;
                }
        }

#pragma unroll
        for (int i = 0; i < 2; ++i) {
            u16* pb = i ? pb1 : pb0;
#pragma unroll
            for (int cb = 0; cb < 5; ++cb)
#pragma unroll
                for (int r = 0; r < 4; ++r) {
                    const float p = fexp2(sac[i][cb][r] - M[i][r]);
                    const int rw = 4 * lg + r;
                    pb[rw * 128 + (((2 * cb + (lr >> 3)) ^ (rw & 15)) * 8) + (lr & 7)] =
                        (u16)(__builtin_bit_cast(u32, p) >> 16);
                }
#pragma unroll
            for (int r = 0; r < 4; ++r) {
                const int rw = 4 * lg + r;
                pb[rw * 128 + (((10 + (lr >> 3)) ^ (rw & 15)) * 8) + (lr & 7)] = 0;
            }
        }

        __builtin_amdgcn_s_setprio(1);
#pragma unroll
        for (int s = 0; s < 3; ++s) {
            const bf16x8 pa0 = *(const bf16x8*)(pb0 + lr * 128 + (((4 * s + lg) ^ (lr & 15)) * 8));
            const bf16x8 pa1 = *(const bf16x8*)(pb1 + lr * 128 + (((4 * s + lg) ^ (lr & 15)) * 8));
            Lac[0] = mfma16(pa0, onesv, Lac[0]);
            Lac[1] = mfma16(pa1, onesv, Lac[1]);
#pragma unroll
            for (int f = 0; f < 4; ++f) {
                const int vr = f * 16 + lr;
                const bf16x8 vb = *(const bf16x8*)(Vc + vr * 128 + (((4 * s + lg) ^ (vr & 15)) * 8));
                acco[0][f] = mfma16(pa0, vb, acco[0][f]);
                acco[1][f] = mfma16(pa1, vb, acco[1][f]);
            }
        }
        __builtin_amdgcn_s_setprio(0);
    }

#pragma unroll
    for (int i = 0; i < 2; ++i)
#pragma unroll
        for (int r = 0; r < 4; ++r) {
            const float inv = __builtin_amdgcn_rcpf(Lac[i][r]);
            const int n = qrow0 + i * 16 + 4 * lg + r;
            if (n < 577) {
#pragma unroll
                for (int f = 0; f < 4; ++f)
                    Og[((size_t)b * 577 + n) * 768 + h * 64 + f * 16 + lr] =
                        f2bf(acco[i][f][r] * inv);
            }
        }
}

// ---------------- launch ----------------
extern "C" void kernel_launch(void* const* d_in, const int* in_sizes, int n_in,
                              void* d_out, int out_size, void* d_ws, size_t ws_size,
                              hipStream_t stream) {
    const float* x      = (const float*)d_in[0];
    const float* W_qkv  = (const float*)d_in[1];
    const float* W_proj = (const float*)d_in[2];
    const float* b_proj = (const float*)d_in[3];
    const float* coef   = (const float*)d_in[4];
    float* out = (float*)d_out;
    char* ws = (char*)d_ws;

    // ws layout with lifetime aliasing (66.1 MB total):
    //   xb : live prep..gemm0  |  Og : live attn..gemm1 (ALIASES xb)
    u16* xb   = (u16*)(ws + 0);                        // 14,180,352
    u16* Og   = (u16*)(ws + 0);                        // aliases xb
    u16* wqkv = (u16*)(ws + 14180352);                 //  3,538,944 (absorbs OOB)
    u16* wprj = (u16*)(ws + 17719296);                 //  1,179,648
    u16* Qg   = (u16*)(ws + 18898944);                 // 15,728,640
    u16* Kg   = (u16*)(ws + 34627584);                 // 15,728,640
    u16* Vtg  = (u16*)(ws + 50356224);                 // 15,728,640 -> 66,084,864
    // No Vtg memset: pad keys get P = exp2(-1e30-M) = 0 exactly; 0*finite = 0.

    k_prep<<<2048, 256, 0, stream>>>(x, W_qkv, W_proj, xb, wqkv, wprj);

    k_gemm2<0, 9><<<37 * 9, 512, 131072, stream>>>(xb, wqkv, Qg, Kg, Vtg,
                                                   nullptr, nullptr);
    k_attn<<<960, 256, 0, stream>>>(Qg, Kg, Vtg, coef, Og);
    k_gemm2<1, 3><<<37 * 3, 512, 131072, stream>>>(Og, wprj, nullptr, nullptr,
                                                   nullptr, out, b_proj);
}

// Round 20
// 157.052 us; speedup vs baseline: 1.2143x; 1.2143x over previous
//
#include <hip/hip_runtime.h>

// PolyRPE attention, MI355X gfx950.  (r18 best-known configuration, reverted
// after the 256x256 8-wave experiment regressed per m196's failure mode.)
// prep (cvt + LDS-tiled transposes) -> QKV GEMM (128x128, BK=32, 4-buffer
// gl_lds, dist-3, vmcnt(8), T2 swizzle, T1 XCD grid) -> fused flash attention
// v5 (KVBLK=128; L row-sums via mfma(P, ones); truncation P-pack; 32 q-rows/
// wave, Horner RPE, P overlays dead K/V staging, 1 barrier/tile) -> proj GEMM.
//
// Dims: B=16, N=577 (pad 640), C=768, h=12, d=64, K=768, 3C=2304.

using u16 = unsigned short;
using u32 = unsigned int;

typedef __bf16 bf16x8 __attribute__((ext_vector_type(8)));
typedef float f32x4 __attribute__((ext_vector_type(4)));

__device__ inline u16 f2bf(float f) {
    u32 u = __builtin_bit_cast(u32, f);
    u32 r = u + 0x7fffu + ((u >> 16) & 1u);   // RNE
    return (u16)(r >> 16);
}
__device__ inline float bf2f(u16 x) {
    return __builtin_bit_cast(float, (u32)x << 16);
}

__device__ inline f32x4 mfma16(bf16x8 a, bf16x8 b, f32x4 c) {
    return __builtin_amdgcn_mfma_f32_16x16x32_bf16(a, b, c, 0, 0, 0);
}

__device__ inline float fexp2(float x) { return __builtin_amdgcn_exp2f(x); }

// bijective XCD chunk remap (m204)
__device__ inline int xcd_remap(int bid, int nwg) {
    const int q = nwg >> 3, r = nwg & 7;
    const int xcd = bid & 7, idx = bid >> 3;
    return (xcd < r ? xcd * (q + 1) : r * (q + 1) + (xcd - r) * q) + idx;
}

// 16-lane (DPP-row) max reduction.
__device__ inline float dpp_max16(float v) {
    int x;
    x = __builtin_amdgcn_update_dpp(0, __builtin_bit_cast(int, v), 0xB1, 0xF, 0xF, true);
    v = fmaxf(v, __builtin_bit_cast(float, x));
    x = __builtin_amdgcn_update_dpp(0, __builtin_bit_cast(int, v), 0x4E, 0xF, 0xF, true);
    v = fmaxf(v, __builtin_bit_cast(float, x));
    x = __builtin_amdgcn_update_dpp(0, __builtin_bit_cast(int, v), 0x124, 0xF, 0xF, true);
    v = fmaxf(v, __builtin_bit_cast(float, x));
    x = __builtin_amdgcn_update_dpp(0, __builtin_bit_cast(int, v), 0x128, 0xF, 0xF, true);
    v = fmaxf(v, __builtin_bit_cast(float, x));
    return v;
}

#define GLOAD_LDS16(g, l)                                                          \
    __builtin_amdgcn_global_load_lds((const __attribute__((address_space(1))) u32*)(g), \
                                     (__attribute__((address_space(3))) u32*)(l), 16, 0, 0)

#define BAR()    asm volatile("s_barrier" ::: "memory")
#define WAITV8() asm volatile("s_waitcnt vmcnt(8)" ::: "memory")
#define WAITV4() asm volatile("s_waitcnt vmcnt(4)" ::: "memory")
#define WAITV0() asm volatile("s_waitcnt vmcnt(0)" ::: "memory")

// ---------------- prep ----------------
__global__ void k_prep(const float* __restrict__ x, const float* __restrict__ Wq,
                       const float* __restrict__ Wp, u16* __restrict__ xb,
                       u16* __restrict__ wqkv, u16* __restrict__ wprj) {
    const int bid = blockIdx.x;
    const int t = threadIdx.x;
    if (bid < 576) {
        __shared__ float tile[64][65];
        const float* src;
        u16* dst;
        int C, rt, ct;
        if (bid < 432) { src = Wq; dst = wqkv; C = 2304; rt = bid / 36; ct = bid % 36; }
        else { const int b2 = bid - 432; src = Wp; dst = wprj; C = 768; rt = b2 / 12; ct = b2 % 12; }
        const int row0 = rt * 64, col0 = ct * 64;
#pragma unroll
        for (int it = 0; it < 4; ++it) {
            const int row = it * 16 + (t >> 4);
            const float4 v = *(const float4*)&src[(size_t)(row0 + row) * C + col0 + (t & 15) * 4];
            tile[row][(t & 15) * 4 + 0] = v.x;
            tile[row][(t & 15) * 4 + 1] = v.y;
            tile[row][(t & 15) * 4 + 2] = v.z;
            tile[row][(t & 15) * 4 + 3] = v.w;
        }
        __syncthreads();
#pragma unroll
        for (int it = 0; it < 4; ++it) {
            const int oc = it * 16 + (t >> 4);
            const int orr = (t & 15) * 4;
            ushort4 o;
            o.x = f2bf(tile[orr + 0][oc]);
            o.y = f2bf(tile[orr + 1][oc]);
            o.z = f2bf(tile[orr + 2][oc]);
            o.w = f2bf(tile[orr + 3][oc]);
            *(ushort4*)&dst[(size_t)(col0 + oc) * 768 + row0 + orr] = o;
        }
    } else {
        const int n4 = 9232 * 768 / 4;
        const int stride = (2048 - 576) * 256;
        for (int i = (bid - 576) * 256 + t; i < n4; i += stride) {
            float4 v = ((const float4*)x)[i];
            ushort4 o;
            o.x = f2bf(v.x); o.y = f2bf(v.y); o.z = f2bf(v.z); o.w = f2bf(v.w);
            ((ushort4*)xb)[i] = o;
        }
    }
}

// ---------------- GEMM (r8-proven: 4-buffer, dist-3, vmcnt(8)) --------------
__device__ inline void stageAB(const u16* __restrict__ Ag, const u16* __restrict__ Bg,
                               u16* L, int t) {
#pragma unroll
    for (int c = 0; c < 2; ++c) {
        const int p = c * 256 + t;
        const int row = p >> 2, ch = p & 3;
        const int src = row * 768 + ((ch ^ ((row >> 1) & 3)) * 8);
        GLOAD_LDS16(Ag + src, L + p * 8);
        GLOAD_LDS16(Bg + src, L + 4096 + p * 8);
    }
}
__device__ inline bf16x8 ldfrag32(const u16* base, int row, int slot) {
    return *(const bf16x8*)(base + row * 32 + ((slot ^ ((row >> 1) & 3)) * 8));
}

template <int MODE, int NB>
__launch_bounds__(256, 2)
__global__ void k_gemm(const u16* __restrict__ A, const u16* __restrict__ Bw,
                       u16* __restrict__ q_out, u16* __restrict__ k_out,
                       u16* __restrict__ v_out,
                       float* __restrict__ f_out, const float* __restrict__ bias) {
    constexpr int NT = 24;
    constexpr int M = 9232;
    const int wgid = xcd_remap(blockIdx.x, gridDim.x);
    const int mbase = (wgid / NB) * 128;
    const int nbase = (wgid - (wgid / NB) * NB) * 128;
    __shared__ alignas(16) u16 lds[4][8192];  // 64 KB -> 2 blocks/CU
    const int t = threadIdx.x;
    const int lane = t & 63, w = t >> 6;
    const int lr = lane & 15, lg = lane >> 4;
    const int wrow = (w >> 1) * 64, wcol = (w & 1) * 64;
    const u16* Ag = A + (size_t)mbase * 768;
    const u16* Bg = Bw + (size_t)nbase * 768;
    f32x4 acc[4][4] = {};

    stageAB(Ag, Bg, &lds[0][0], t);
    stageAB(Ag + 32, Bg + 32, &lds[1][0], t);
    stageAB(Ag + 64, Bg + 64, &lds[2][0], t);
    WAITV8();
    BAR();

    for (int kt = 0; kt < NT; ++kt) {
        const u16* Lc = &lds[kt & 3][0];
        if (kt + 3 < NT)
            stageAB(Ag + (kt + 3) * 32, Bg + (kt + 3) * 32, &lds[(kt + 3) & 3][0], t);
        bf16x8 af[4], bv[4];
#pragma unroll
        for (int i = 0; i < 4; ++i)
            af[i] = ldfrag32(Lc, wrow + i * 16 + lr, lg);
#pragma unroll
        for (int j = 0; j < 4; ++j)
            bv[j] = ldfrag32(Lc + 4096, wcol + j * 16 + lr, lg);
        __builtin_amdgcn_s_setprio(1);
#pragma unroll
        for (int i = 0; i < 4; ++i)
#pragma unroll
            for (int j = 0; j < 4; ++j)
                acc[i][j] = mfma16(af[i], bv[j], acc[i][j]);
        __builtin_amdgcn_s_setprio(0);
        if (kt + 1 < NT) {
            if (kt < NT - 3)       { WAITV8(); }
            else if (kt == NT - 3) { WAITV4(); }
            else                   { WAITV0(); }
            BAR();
        }
    }

#pragma unroll
    for (int i = 0; i < 4; ++i) {
#pragma unroll
        for (int j = 0; j < 4; ++j) {
            const int col = nbase + wcol + j * 16 + lr;
#pragma unroll
            for (int r = 0; r < 4; ++r) {
                const int row = mbase + wrow + i * 16 + 4 * lg + r;
                if (row < M) {
                    if (MODE == 0) {
                        const int bb = row / 577;
                        const int nn = row - bb * 577;
                        const int tt = col / 768;
                        const int rem = col - tt * 768;
                        const int hh = rem >> 6, dd = rem & 63;
                        const size_t bh = (size_t)bb * 12 + hh;
                        const u16 val = f2bf(acc[i][j][r]);
                        if (tt == 0)      q_out[(bh * 640 + nn) * 64 + dd] = val;
                        else if (tt == 1) k_out[(bh * 640 + nn) * 64 + dd] = val;
                        else              v_out[(bh * 64 + dd) * 640 + nn] = val;
                    } else {
                        f_out[(size_t)row * 768 + col] = acc[i][j][r] + bias[col];
                    }
                }
            }
        }
    }
}

// ---------------- fused attention v5 (KVBLK=128, all 577 q rows) ------------
__launch_bounds__(256, 2)
__global__ void k_attn(const u16* __restrict__ Qg, const u16* __restrict__ Kg,
                       const u16* __restrict__ Vtg, const float* __restrict__ coef,
                       u16* __restrict__ Og) {
    const int wgid = xcd_remap(blockIdx.x, gridDim.x);   // 960 = 8*120 exact
    const int bh = wgid / 5;
    const int qt = wgid - bh * 5;       // 0..4
    const int b = bh / 12, h = bh - b * 12;
    const int t = threadIdx.x;
    const int lane = t & 63, w = t >> 6;
    const int lr = lane & 15, lg = lane >> 4;
    __shared__ alignas(16) u16 Kl[2][8192];   // [128 keys][64 d]
    __shared__ alignas(16) u16 Vl[2][8192];   // [64 d][128 keys]

    const float l2e = 1.4426950408889634f;
    const float hc0 = coef[h * 4 + 0] * l2e, hc1 = coef[h * 4 + 1] * l2e,
                hc2 = coef[h * 4 + 2] * l2e, hc3 = coef[h * 4 + 3] * l2e;

    bf16x8 onesv;
#pragma unroll
    for (int j = 0; j < 8; ++j) onesv[j] = (__bf16)1.0f;

    const int qrow0 = qt * 128 + w * 32;
    bf16x8 qa[2][2];
#pragma unroll
    for (int i = 0; i < 2; ++i) {
        const u16* qp = Qg + ((size_t)bh * 640 + qrow0 + i * 16 + lr) * 64;
        qa[i][0] = *(const bf16x8*)(qp + lg * 8);
        qa[i][1] = *(const bf16x8*)(qp + 32 + lg * 8);
    }

    float gi[2][4], gj[2][4], nvf[2][4];
#pragma unroll
    for (int i = 0; i < 2; ++i)
#pragma unroll
        for (int r = 0; r < 4; ++r) {
            const int n = qrow0 + i * 16 + 4 * lg + r;
            nvf[i][r] = (n == 0) ? 0.f : 1.f;
            const int nm1 = (n > 0) ? n - 1 : 0;
            const int qi = nm1 / 24;
            gi[i][r] = (float)qi;
            gj[i][r] = (float)(nm1 - qi * 24);
        }

    float M[2][4];
    f32x4 Lac[2] = {};
#pragma unroll
    for (int i = 0; i < 2; ++i)
#pragma unroll
        for (int r = 0; r < 4; ++r) M[i][r] = -3e38f;
    f32x4 acco[2][4] = {};
    const float scale2 = 0.125f * 1.4426950408889634f;
    const int ch0 = ((lg ^ (lr & 7))) * 8;    // K read chunk (d-dim)

    const u16* Ksb = Kg + (size_t)bh * 640 * 64;
    const u16* Vsb = Vtg + (size_t)bh * 64 * 640;
    const int krow = 32 * w + (lane >> 1), kch0 = (lane & 1) * 4;
    const int vrow = 16 * w + (lane >> 2), vch0 = (lane & 3) * 4;

    {   // prologue: tile 0 -> regs -> LDS buf 0
#pragma unroll
        for (int q = 0; q < 4; ++q) {
            uint4 kv = *(const uint4*)(Ksb + (size_t)krow * 64 + (kch0 + q) * 8);
            *(uint4*)(&Kl[0][krow * 64 + (((kch0 + q) ^ (krow & 7)) * 8)]) = kv;
            uint4 vv = *(const uint4*)(Vsb + (size_t)vrow * 640 + (vch0 + q) * 8);
            *(uint4*)(&Vl[0][vrow * 128 + (((vch0 + q) ^ (vrow & 15)) * 8)]) = vv;
        }
    }
    __syncthreads();
    int cur = 0;

    for (int kt = 0; kt < 4; ++kt) {
        const u16* Kc = &Kl[cur][0];
        const u16* Vc = &Vl[cur][0];
        u16* pb0 = &Kl[cur ^ 1][32 * w * 64];     // frag 0 P: 16 x 128
        u16* pb1 = &Vl[cur ^ 1][16 * w * 128];    // frag 1 P: 16 x 128

        // S = Q K^T (8 column blocks)
        f32x4 sac[2][8];
        __builtin_amdgcn_s_setprio(1);
#pragma unroll
        for (int cb = 0; cb < 8; ++cb) {
            const int row = cb * 16 + lr;
            const bf16x8 kb0 = *(const bf16x8*)(Kc + row * 64 + ch0);
            const bf16x8 kb1 = *(const bf16x8*)(Kc + row * 64 + (ch0 ^ 32));
#pragma unroll
            for (int i = 0; i < 2; ++i) {
                f32x4 z = {};
                z = mfma16(qa[i][0], kb0, z);
                sac[i][cb] = mfma16(qa[i][1], kb1, z);
            }
        }
        __builtin_amdgcn_s_setprio(0);

        // fold scale + Horner RPE; per-row tile max
        float tm[2][4];
#pragma unroll
        for (int i = 0; i < 2; ++i)
#pragma unroll
            for (int r = 0; r < 4; ++r) tm[i][r] = -3e38f;
#pragma unroll
        for (int cb = 0; cb < 8; ++cb) {
            const int m = kt * 128 + cb * 16 + lr;
            const float mvf = (m == 0) ? 0.f : 1.f;
            const int mm1 = (m > 0) ? m - 1 : 0;
            const int pi = mm1 / 24;
            const float ci = (float)pi;
            const float cj = (float)(mm1 - pi * 24);
#pragma unroll
            for (int i = 0; i < 2; ++i)
#pragma unroll
                for (int r = 0; r < 4; ++r) {
                    const float d = fabsf(gi[i][r] - ci) + fabsf(gj[i][r] - cj);
                    float rp = fmaf(hc3, d, hc2);
                    rp = fmaf(rp, d, hc1);
                    rp = fmaf(rp, d, hc0);
                    const float v = fmaf(sac[i][cb][r], scale2,
                                         rp * (mvf * nvf[i][r]));
                    sac[i][cb][r] = v;
                    tm[i][r] = fmaxf(tm[i][r], v);
                }
        }
#pragma unroll
        for (int i = 0; i < 2; ++i)
#pragma unroll
            for (int r = 0; r < 4; ++r) tm[i][r] = dpp_max16(tm[i][r]);

        float over = -3e38f;
#pragma unroll
        for (int i = 0; i < 2; ++i)
#pragma unroll
            for (int r = 0; r < 4; ++r) over = fmaxf(over, tm[i][r] - M[i][r]);
        if (__any(over > 11.5f)) {
#pragma unroll
            for (int i = 0; i < 2; ++i)
#pragma unroll
                for (int r = 0; r < 4; ++r) {
                    const float Mn = fmaxf(M[i][r], tm[i][r]);
                    const float a = fexp2(M[i][r] - Mn);
                    Lac[i][r] *= a;
                    acco[i][0][r] *= a; acco[i][1][r] *= a;
                    acco[i][2][r] *= a; acco[i][3][r] *= a;
                    M[i][r] = Mn;
                }
        }

        // p = 2^(sac-M) -> P regions (truncation pack; L via MFMA below)
#pragma unroll
        for (int i = 0; i < 2; ++i) {
            u16* pb = i ? pb1 : pb0;
#pragma unroll
            for (int cb = 0; cb < 8; ++cb)
#pragma unroll
                for (int r = 0; r < 4; ++r) {
                    const float p = fexp2(sac[i][cb][r] - M[i][r]);
                    const int rw = 4 * lg + r;
                    pb[rw * 128 + (((2 * cb + (lr >> 3)) ^ (rw & 15)) * 8) + (lr & 7)] =
                        (u16)(__builtin_bit_cast(u32, p) >> 16);
                }
        }

        // issue next-tile loads; PV below covers latency
        uint4 nk[4], nv[4];
        {
            const u16* Ks = Ksb + (size_t)(kt + 1) * 128 * 64;
            const u16* Vs = Vsb + (size_t)(kt + 1) * 128;
#pragma unroll
            for (int q = 0; q < 4; ++q) {
                nk[q] = *(const uint4*)(Ks + (size_t)krow * 64 + (kch0 + q) * 8);
                nv[q] = *(const uint4*)(Vs + (size_t)vrow * 640 + (vch0 + q) * 8);
            }
        }

        // PV + L row-sums: 4 k-slices of 32 keys
        __builtin_amdgcn_s_setprio(1);
#pragma unroll
        for (int s = 0; s < 4; ++s) {
            const bf16x8 pa0 = *(const bf16x8*)(pb0 + lr * 128 + (((4 * s + lg) ^ (lr & 15)) * 8));
            const bf16x8 pa1 = *(const bf16x8*)(pb1 + lr * 128 + (((4 * s + lg) ^ (lr & 15)) * 8));
            Lac[0] = mfma16(pa0, onesv, Lac[0]);
            Lac[1] = mfma16(pa1, onesv, Lac[1]);
#pragma unroll
            for (int f = 0; f < 4; ++f) {
                const int vr = f * 16 + lr;
                const bf16x8 vb = *(const bf16x8*)(Vc + vr * 128 + (((4 * s + lg) ^ (vr & 15)) * 8));
                acco[0][f] = mfma16(pa0, vb, acco[0][f]);
                acco[1][f] = mfma16(pa1, vb, acco[1][f]);
            }
        }
        __builtin_amdgcn_s_setprio(0);

        // land prefetched tile into own regions (after own P reads)
#pragma unroll
        for (int q = 0; q < 4; ++q) {
            *(uint4*)(&Kl[cur ^ 1][krow * 64 + (((kch0 + q) ^ (krow & 7)) * 8)]) = nk[q];
            *(uint4*)(&Vl[cur ^ 1][vrow * 128 + (((vch0 + q) ^ (vrow & 15)) * 8)]) = nv[q];
        }
        __syncthreads();
        cur ^= 1;
    }

    {   // ---- peeled tail (keys 512..639): cb 0..3 full, cb4 only key 576 ----
        const u16* Kc = &Kl[cur][0];
        const u16* Vc = &Vl[cur][0];
        u16* pb0 = &Kl[cur ^ 1][32 * w * 64];
        u16* pb1 = &Vl[cur ^ 1][16 * w * 128];

        f32x4 sac[2][5];
        __builtin_amdgcn_s_setprio(1);
#pragma unroll
        for (int cb = 0; cb < 5; ++cb) {
            const int row = cb * 16 + lr;
            const bf16x8 kb0 = *(const bf16x8*)(Kc + row * 64 + ch0);
            const bf16x8 kb1 = *(const bf16x8*)(Kc + row * 64 + (ch0 ^ 32));
#pragma unroll
            for (int i = 0; i < 2; ++i) {
                f32x4 z = {};
                z = mfma16(qa[i][0], kb0, z);
                sac[i][cb] = mfma16(qa[i][1], kb1, z);
            }
        }
        __builtin_amdgcn_s_setprio(0);

        float tm[2][4];
#pragma unroll
        for (int i = 0; i < 2; ++i)
#pragma unroll
            for (int r = 0; r < 4; ++r) tm[i][r] = -3e38f;
#pragma unroll
        for (int cb = 0; cb < 5; ++cb) {
            const int m = 512 + cb * 16 + lr;
            const bool valid = (m <= 576);
            const int mm1 = m - 1;
            const int pi = mm1 / 24;
            const float ci = (float)((pi < 24) ? pi : 23);
            const float cj = (float)((pi < 24) ? (mm1 - pi * 24) : 23);
#pragma unroll
            for (int i = 0; i < 2; ++i)
#pragma unroll
                for (int r = 0; r < 4; ++r) {
                    const float d = fabsf(gi[i][r] - ci) + fabsf(gj[i][r] - cj);
                    float rp = fmaf(hc3, d, hc2);
                    rp = fmaf(rp, d, hc1);
                    rp = fmaf(rp, d, hc0);
                    float v = fmaf(sac[i][cb][r], scale2, rp * nvf[i][r]);
                    v = valid ? v : -1e30f;
                    sac[i][cb][r] = v;
                    tm[i][r] = fmaxf(tm[i][r], v);
                }
        }
#pragma unroll
        for (int i = 0; i < 2; ++i)
#pragma unroll
            for (int r = 0; r < 4; ++r) tm[i][r] = dpp_max16(tm[i][r]);

        float over = -3e38f;
#pragma unroll
        for (int i = 0; i < 2; ++i)
#pragma unroll
            for (int r = 0; r < 4; ++r) over = fmaxf(over, tm[i][r] - M[i][r]);
        if (__any(over > 11.5f)) {
#pragma unroll
            for (int i = 0; i < 2; ++i)
#pragma unroll
                for (int r = 0; r < 4; ++r) {
                    const float Mn = fmaxf(M[i][r], tm[i][r]);
                    const float a = fexp2(M[i][r] - Mn);
                    Lac[i][r] *= a;
                    acco[i][0][r] *= a; acco[i][1][r] *= a;
                    acco[i][2][r] *= a; acco[i][3][r] *= a;
                    M[i][r] = Mn;
                }
        }

#pragma unroll
        for (int i = 0; i < 2; ++i) {
            u16* pb = i ? pb1 : pb0;
#pragma unroll
            for (int cb = 0; cb < 5; ++cb)
#pragma unroll
                for (int r = 0; r < 4; ++r) {
                    const float p = fexp2(sac[i][cb][r] - M[i][r]);
                    const int rw = 4 * lg + r;
                    pb[rw * 128 + (((2 * cb + (lr >> 3)) ^ (rw & 15)) * 8) + (lr & 7)] =
                        (u16)(__builtin_bit_cast(u32, p) >> 16);
                }
            // zero P for cb5 (chunks 10,11): read by PV k-slice s=2
#pragma unroll
            for (int r = 0; r < 4; ++r) {
                const int rw = 4 * lg + r;
                pb[rw * 128 + (((10 + (lr >> 3)) ^ (rw & 15)) * 8) + (lr & 7)] = 0;
            }
        }

        // PV + L: k-slices 0..2 (keys 512..607); slice 3 all-invalid, skipped
        __builtin_amdgcn_s_setprio(1);
#pragma unroll
        for (int s = 0; s < 3; ++s) {
            const bf16x8 pa0 = *(const bf16x8*)(pb0 + lr * 128 + (((4 * s + lg) ^ (lr & 15)) * 8));
            const bf16x8 pa1 = *(const bf16x8*)(pb1 + lr * 128 + (((4 * s + lg) ^ (lr & 15)) * 8));
            Lac[0] = mfma16(pa0, onesv, Lac[0]);
            Lac[1] = mfma16(pa1, onesv, Lac[1]);
#pragma unroll
            for (int f = 0; f < 4; ++f) {
                const int vr = f * 16 + lr;
                const bf16x8 vb = *(const bf16x8*)(Vc + vr * 128 + (((4 * s + lg) ^ (vr & 15)) * 8));
                acco[0][f] = mfma16(pa0, vb, acco[0][f]);
                acco[1][f] = mfma16(pa1, vb, acco[1][f]);
            }
        }
        __builtin_amdgcn_s_setprio(0);
    }

#pragma unroll
    for (int i = 0; i < 2; ++i)
#pragma unroll
        for (int r = 0; r < 4; ++r) {
            const float inv = __builtin_amdgcn_rcpf(Lac[i][r]);
            const int n = qrow0 + i * 16 + 4 * lg + r;
            if (n < 577) {
#pragma unroll
                for (int f = 0; f < 4; ++f)
                    Og[((size_t)b * 577 + n) * 768 + h * 64 + f * 16 + lr] =
                        f2bf(acco[i][f][r] * inv);
            }
        }
}

// ---------------- launch ----------------
extern "C" void kernel_launch(void* const* d_in, const int* in_sizes, int n_in,
                              void* d_out, int out_size, void* d_ws, size_t ws_size,
                              hipStream_t stream) {
    const float* x      = (const float*)d_in[0];
    const float* W_qkv  = (const float*)d_in[1];
    const float* W_proj = (const float*)d_in[2];
    const float* b_proj = (const float*)d_in[3];
    const float* coef   = (const float*)d_in[4];
    float* out = (float*)d_out;
    char* ws = (char*)d_ws;

    // ws layout with lifetime aliasing (66.1 MB total):
    //   xb : live prep..gemm0  |  Og : live attn..gemm1 (ALIASES xb)
    u16* xb   = (u16*)(ws + 0);                        // 14,180,352
    u16* Og   = (u16*)(ws + 0);                        // aliases xb
    u16* wqkv = (u16*)(ws + 14180352);                 //  3,538,944 (absorbs OOB)
    u16* wprj = (u16*)(ws + 17719296);                 //  1,179,648
    u16* Qg   = (u16*)(ws + 18898944);                 // 15,728,640
    u16* Kg   = (u16*)(ws + 34627584);                 // 15,728,640
    u16* Vtg  = (u16*)(ws + 50356224);                 // 15,728,640 -> 66,084,864
    // No Vtg memset: pad keys get P = exp2(-1e30-M) = 0 exactly; 0*finite = 0.

    k_prep<<<2048, 256, 0, stream>>>(x, W_qkv, W_proj, xb, wqkv, wprj);

    k_gemm<0, 18><<<18 * 73, 256, 0, stream>>>(xb, wqkv, Qg, Kg, Vtg,
                                               nullptr, nullptr);
    k_attn<<<960, 256, 0, stream>>>(Qg, Kg, Vtg, coef, Og);
    k_gemm<1, 6><<<6 * 73, 256, 0, stream>>>(Og, wprj, nullptr, nullptr,
                                             nullptr, out, b_proj);
}